// Round 1
// baseline (447.668 us; speedup 1.0000x reference)
//
#include <hip/hip_runtime.h>

typedef short s16x8 __attribute__((ext_vector_type(8)));
typedef unsigned short u16x8 __attribute__((ext_vector_type(8)));
typedef float f32x16 __attribute__((ext_vector_type(16)));

__device__ __forceinline__ unsigned short f2bf(float f) {
  unsigned u = __float_as_uint(f);
  u += 0x7fffu + ((u >> 16) & 1u);            // round-to-nearest-even
  return (unsigned short)(u >> 16);
}

__device__ __forceinline__ float tanh_fast(float x) {
  // tanh(x) = (e^{2x}-1)/(e^{2x}+1); clamp so exp2 never overflows
  float xc = fminf(15.f, fmaxf(-15.f, x));
  float t = __builtin_amdgcn_exp2f(xc * 2.8853900817779268f); // 2*log2(e)
  return (t - 1.f) * __builtin_amdgcn_rcpf(t + 1.f);
}

// ---- prep: W (K,N) fp32 -> WT (N,K) bf16 in workspace ----
// w1t: 512x256 at ws+0 ; w2t: 512x512 at ws+131072 ; w3t: 128x512 at ws+393216
__global__ void prep_weights(const float* __restrict__ W1, const float* __restrict__ W2,
                             const float* __restrict__ W3, unsigned short* __restrict__ ws) {
  int i = blockIdx.x * 256 + threadIdx.x;
  if (i < 131072) {                  // W1T[n][k], n<512, k<256
    int n = i >> 8, k = i & 255;
    ws[i] = f2bf(W1[k * 512 + n]);
  } else if (i < 393216) {           // W2T[n][k], n<512, k<512
    int j = i - 131072;
    int n = j >> 9, k = j & 511;
    ws[131072 + j] = f2bf(W2[k * 512 + n]);
  } else if (i < 458752) {           // W3T[n][k], n<128, k<512
    int j = i - 393216;
    int n = j >> 9, k = j & 511;
    ws[393216 + j] = f2bf(W3[k * 128 + n]);
  }
}

// Fused 3-layer MLP, one 64-row tile per block.
// LDS: single 64x512 bf16 buffer (64KB). x staged bf16 into first 64x256 region.
// XOR swizzle: 16B chunk c of row m stored at chunk (c ^ (m&7)) -> conflict-free ds_read_b128.
__global__ __launch_bounds__(256, 2)
void mlp_limit_kernel(const float* __restrict__ x,
                      const float* __restrict__ b1, const float* __restrict__ b2,
                      const float* __restrict__ b3,
                      const unsigned short* __restrict__ w1t,
                      const unsigned short* __restrict__ w2t,
                      const unsigned short* __restrict__ w3t,
                      float* __restrict__ out) {
  __shared__ __align__(16) unsigned short lds[64 * 512];  // 64KB
  const int tid   = threadIdx.x;
  const int lane  = tid & 63;
  const int wave  = tid >> 6;
  const int ln31  = lane & 31;
  const int khalf = lane >> 5;            // 0/1: which 8-wide k-half of the frag
  const int m0    = blockIdx.x * 64;

  // ---- stage x tile (64 x 256 fp32 -> bf16, swizzled 16B chunks) ----
  for (int c = tid; c < 2048; c += 256) { // 64 rows * 32 chunks
    int row = c >> 5, chunk = c & 31;
    const float4* src = (const float4*)(x + (size_t)(m0 + row) * 256 + chunk * 8);
    float4 f0 = src[0], f1 = src[1];
    u16x8 v;
    v[0] = f2bf(f0.x); v[1] = f2bf(f0.y); v[2] = f2bf(f0.z); v[3] = f2bf(f0.w);
    v[4] = f2bf(f1.x); v[5] = f2bf(f1.y); v[6] = f2bf(f1.z); v[7] = f2bf(f1.w);
    *(u16x8*)&lds[row * 256 + ((chunk ^ (row & 7)) << 3)] = v;
  }
  __syncthreads();

  const int ncol0 = wave * 128;           // each wave owns 128 hidden cols

  // ---- Layer 1: h1 = tanh(x @ W1 + b1), wave tile 64x128, K=256 ----
  f32x16 acc[2][4];
  #pragma unroll
  for (int mt = 0; mt < 2; ++mt)
    #pragma unroll
    for (int nt = 0; nt < 4; ++nt)
      #pragma unroll
      for (int r = 0; r < 16; ++r) acc[mt][nt][r] = 0.f;

  #pragma unroll 4
  for (int kk = 0; kk < 16; ++kk) {
    const int k = kk * 16 + khalf * 8;
    const int ch = k >> 3;
    s16x8 a[2];
    #pragma unroll
    for (int mt = 0; mt < 2; ++mt) {
      int m = mt * 32 + ln31;
      a[mt] = *(const s16x8*)&lds[m * 256 + ((ch ^ (m & 7)) << 3)];
    }
    s16x8 b[4];
    #pragma unroll
    for (int nt = 0; nt < 4; ++nt) {
      int n = ncol0 + nt * 32 + ln31;
      b[nt] = *(const s16x8*)(w1t + n * 256 + k);
    }
    #pragma unroll
    for (int mt = 0; mt < 2; ++mt)
      #pragma unroll
      for (int nt = 0; nt < 4; ++nt)
        acc[mt][nt] = __builtin_amdgcn_mfma_f32_32x32x16_bf16(a[mt], b[nt], acc[mt][nt], 0, 0, 0);
  }
  __syncthreads();                         // all x reads done before overwrite

  {
    float bias[4];
    #pragma unroll
    for (int nt = 0; nt < 4; ++nt) bias[nt] = b1[ncol0 + nt * 32 + ln31];
    #pragma unroll
    for (int mt = 0; mt < 2; ++mt)
      #pragma unroll
      for (int nt = 0; nt < 4; ++nt) {
        int hc = ncol0 + nt * 32 + ln31;
        #pragma unroll
        for (int r = 0; r < 16; ++r) {
          int m = mt * 32 + (r & 3) + 8 * (r >> 2) + 4 * khalf;   // C/D row map (m74/m101)
          float v = tanh_fast(acc[mt][nt][r] + bias[nt]);
          lds[m * 512 + ((((hc >> 3) ^ (m & 7))) << 3) + (hc & 7)] = f2bf(v);
        }
      }
  }
  __syncthreads();

  // ---- Layer 2: h2 = tanh(h1 @ W2 + b2), wave tile 64x128, K=512 ----
  #pragma unroll
  for (int mt = 0; mt < 2; ++mt)
    #pragma unroll
    for (int nt = 0; nt < 4; ++nt)
      #pragma unroll
      for (int r = 0; r < 16; ++r) acc[mt][nt][r] = 0.f;

  #pragma unroll 4
  for (int kk = 0; kk < 32; ++kk) {
    const int k = kk * 16 + khalf * 8;
    const int ch = k >> 3;
    s16x8 a[2];
    #pragma unroll
    for (int mt = 0; mt < 2; ++mt) {
      int m = mt * 32 + ln31;
      a[mt] = *(const s16x8*)&lds[m * 512 + ((ch ^ (m & 7)) << 3)];
    }
    s16x8 b[4];
    #pragma unroll
    for (int nt = 0; nt < 4; ++nt) {
      int n = ncol0 + nt * 32 + ln31;
      b[nt] = *(const s16x8*)(w2t + n * 512 + k);
    }
    #pragma unroll
    for (int mt = 0; mt < 2; ++mt)
      #pragma unroll
      for (int nt = 0; nt < 4; ++nt)
        acc[mt][nt] = __builtin_amdgcn_mfma_f32_32x32x16_bf16(a[mt], b[nt], acc[mt][nt], 0, 0, 0);
  }
  __syncthreads();                         // all h1 reads done before overwrite

  {
    float bias[4];
    #pragma unroll
    for (int nt = 0; nt < 4; ++nt) bias[nt] = b2[ncol0 + nt * 32 + ln31];
    #pragma unroll
    for (int mt = 0; mt < 2; ++mt)
      #pragma unroll
      for (int nt = 0; nt < 4; ++nt) {
        int hc = ncol0 + nt * 32 + ln31;
        #pragma unroll
        for (int r = 0; r < 16; ++r) {
          int m = mt * 32 + (r & 3) + 8 * (r >> 2) + 4 * khalf;
          float v = tanh_fast(acc[mt][nt][r] + bias[nt]);
          lds[m * 512 + ((((hc >> 3) ^ (m & 7))) << 3) + (hc & 7)] = f2bf(v);
        }
      }
  }
  __syncthreads();

  // ---- Layer 3: out = h2 @ W3 + b3, wave tile 64x32, K=512 ----
  f32x16 acc3[2];
  #pragma unroll
  for (int mt = 0; mt < 2; ++mt)
    #pragma unroll
    for (int r = 0; r < 16; ++r) acc3[mt][r] = 0.f;

  const int n3 = wave * 32 + ln31;         // 4 waves * 32 = 128 output cols
  #pragma unroll 4
  for (int kk = 0; kk < 32; ++kk) {
    const int k = kk * 16 + khalf * 8;
    const int ch = k >> 3;
    s16x8 a0 = *(const s16x8*)&lds[ln31 * 512 + ((ch ^ (ln31 & 7)) << 3)];
    s16x8 a1 = *(const s16x8*)&lds[(32 + ln31) * 512 + ((ch ^ (ln31 & 7)) << 3)];
    s16x8 b  = *(const s16x8*)(w3t + n3 * 512 + k);
    acc3[0] = __builtin_amdgcn_mfma_f32_32x32x16_bf16(a0, b, acc3[0], 0, 0, 0);
    acc3[1] = __builtin_amdgcn_mfma_f32_32x32x16_bf16(a1, b, acc3[1], 0, 0, 0);
  }

  {
    float bias3 = b3[n3];
    #pragma unroll
    for (int mt = 0; mt < 2; ++mt)
      #pragma unroll
      for (int r = 0; r < 16; ++r) {
        int m = m0 + mt * 32 + (r & 3) + 8 * (r >> 2) + 4 * khalf;
        out[(size_t)m * 128 + n3] = acc3[mt][r] + bias3;
      }
  }
}

extern "C" void kernel_launch(void* const* d_in, const int* in_sizes, int n_in,
                              void* d_out, int out_size, void* d_ws, size_t ws_size,
                              hipStream_t stream) {
  const float* x  = (const float*)d_in[0];
  const float* W1 = (const float*)d_in[1];
  const float* b1 = (const float*)d_in[2];
  const float* W2 = (const float*)d_in[3];
  const float* b2 = (const float*)d_in[4];
  const float* W3 = (const float*)d_in[5];
  const float* b3 = (const float*)d_in[6];
  float* out = (float*)d_out;
  unsigned short* ws = (unsigned short*)d_ws;   // 458752 bf16 = 896KB

  hipLaunchKernelGGL(prep_weights, dim3(1792), dim3(256), 0, stream, W1, W2, W3, ws);
  hipLaunchKernelGGL(mlp_limit_kernel, dim3(2048), dim3(256), 0, stream,
                     x, b1, b2, b3, ws, ws + 131072, ws + 393216, out);
}

// Round 2
// 394.381 us; speedup vs baseline: 1.1351x; 1.1351x over previous
//
#include <hip/hip_runtime.h>

typedef short s16x8 __attribute__((ext_vector_type(8)));
typedef unsigned short u16x8 __attribute__((ext_vector_type(8)));
typedef float f32x16 __attribute__((ext_vector_type(16)));

__device__ __forceinline__ unsigned short f2bf(float f) {
  unsigned u = __float_as_uint(f);
  u += 0x7fffu + ((u >> 16) & 1u);            // round-to-nearest-even
  return (unsigned short)(u >> 16);
}

__device__ __forceinline__ float tanh_fast(float x) {
  float xc = fminf(15.f, fmaxf(-15.f, x));
  float t = __builtin_amdgcn_exp2f(xc * 2.8853900817779268f); // 2*log2(e)
  return (t - 1.f) * __builtin_amdgcn_rcpf(t + 1.f);
}

// ---- prep: pack W (K,N) fp32 -> bf16 MFMA-B-fragment order ----
// chunk c = ((tile*KK + kk)*64 + lane), elems j=0..7:
//   value = W[(kk*16 + (lane>>5)*8 + j) * N + tile*32 + (lane&31)]
// w1p: 16 tiles x 16 kk  at ws+0       (131072 elems)
// w2p: 16 tiles x 32 kk  at ws+131072  (262144 elems)
// w3p:  4 tiles x 32 kk  at ws+393216  ( 65536 elems)
__global__ void prep_pack(const float* __restrict__ W1, const float* __restrict__ W2,
                          const float* __restrict__ W3, unsigned short* __restrict__ ws) {
  int c = blockIdx.x * 256 + threadIdx.x;
  if (c >= 57344) return;
  const float* src; unsigned short* dst; int N, tile, kk, lane;
  if (c < 16384)      { tile = c >> 10;              kk = (c >> 6) & 15; lane = c & 63; src = W1; N = 512; dst = ws + (size_t)c * 8; }
  else if (c < 49152) { int g = c - 16384; tile = g >> 11; kk = (g >> 6) & 31; lane = g & 63; src = W2; N = 512; dst = ws + 131072 + (size_t)g * 8; }
  else                { int g = c - 49152; tile = g >> 11; kk = (g >> 6) & 31; lane = g & 63; src = W3; N = 128; dst = ws + 393216 + (size_t)g * 8; }
  int n  = tile * 32 + (lane & 31);
  int k0 = kk * 16 + (lane >> 5) * 8;
  #pragma unroll
  for (int j = 0; j < 8; ++j) dst[j] = f2bf(src[(size_t)(k0 + j) * N + n]);
}

// LDS layout: chunk-major with row rotation.
// element addr (shorts) = ch*512 + ((row+ch)&63)*8 + within
//  - A-frag reads (fixed ch, consecutive rows): contiguous 512B -> conflict-free
//  - epilogue b16 writes (fixed row, consecutive cols): 32 banks, dword-pair share -> conflict-free
#define LDSIDX(ch, row) (((ch) << 9) + ((((row) + (ch)) & 63) << 3))

__global__ __launch_bounds__(512, 4)
void mlp_limit_kernel(const float* __restrict__ x,
                      const float* __restrict__ b1, const float* __restrict__ b2,
                      const float* __restrict__ b3,
                      const unsigned short* __restrict__ w1p,
                      const unsigned short* __restrict__ w2p,
                      const unsigned short* __restrict__ w3p,
                      float* __restrict__ out) {
  __shared__ __align__(16) unsigned short lds[64 * 512];  // 64KB
  const int tid   = threadIdx.x;
  const int w     = tid >> 6;          // 8 waves
  const int lane  = tid & 63;
  const int ln31  = lane & 31;
  const int khalf = lane >> 5;
  const int m0    = blockIdx.x * 64;

  // ---- stage x tile: 64 rows x 32 chunks (fp32 -> bf16) ----
  #pragma unroll
  for (int c = tid; c < 2048; c += 512) {
    int row = c >> 5, ch = c & 31;
    const float4* src = (const float4*)(x + (size_t)(m0 + row) * 256 + ch * 8);
    float4 f0 = src[0], f1 = src[1];
    u16x8 v;
    v[0] = f2bf(f0.x); v[1] = f2bf(f0.y); v[2] = f2bf(f0.z); v[3] = f2bf(f0.w);
    v[4] = f2bf(f1.x); v[5] = f2bf(f1.y); v[6] = f2bf(f1.z); v[7] = f2bf(f1.w);
    *(u16x8*)&lds[LDSIDX(ch, row)] = v;
  }
  __syncthreads();

  const int ncb = w * 64;              // this wave's 64 hidden cols

  f32x16 acc[2][2];
  #pragma unroll
  for (int mt = 0; mt < 2; ++mt)
    #pragma unroll
    for (int nt = 0; nt < 2; ++nt)
      #pragma unroll
      for (int r = 0; r < 16; ++r) acc[mt][nt][r] = 0.f;

  // ---- Layer 1: K=256 (16 kk), wave tile 64x64 ----
  {
    const s16x8* b0p = (const s16x8*)w1p + (size_t)(w * 2) * 16 * 64 + lane;
    const s16x8* b1p = b0p + 16 * 64;
    #pragma unroll 8
    for (int kk = 0; kk < 16; ++kk) {
      int ch = kk * 2 + khalf;
      s16x8 a0 = *(const s16x8*)&lds[LDSIDX(ch, ln31)];
      s16x8 a1 = *(const s16x8*)&lds[LDSIDX(ch, 32 + ln31)];
      s16x8 b0 = b0p[kk * 64];
      s16x8 b1 = b1p[kk * 64];
      acc[0][0] = __builtin_amdgcn_mfma_f32_32x32x16_bf16(a0, b0, acc[0][0], 0, 0, 0);
      acc[0][1] = __builtin_amdgcn_mfma_f32_32x32x16_bf16(a0, b1, acc[0][1], 0, 0, 0);
      acc[1][0] = __builtin_amdgcn_mfma_f32_32x32x16_bf16(a1, b0, acc[1][0], 0, 0, 0);
      acc[1][1] = __builtin_amdgcn_mfma_f32_32x32x16_bf16(a1, b1, acc[1][1], 0, 0, 0);
    }
  }
  __syncthreads();

  {
    float bias[2];
    bias[0] = b1[ncb + ln31];
    bias[1] = b1[ncb + 32 + ln31];
    #pragma unroll
    for (int mt = 0; mt < 2; ++mt)
      #pragma unroll
      for (int nt = 0; nt < 2; ++nt) {
        int hc = ncb + nt * 32 + ln31;
        int chh = hc >> 3, wi = hc & 7;
        #pragma unroll
        for (int r = 0; r < 16; ++r) {
          int m = mt * 32 + (r & 3) + 8 * (r >> 2) + 4 * khalf;
          lds[(chh << 9) + (((m + chh) & 63) << 3) + wi] =
              f2bf(tanh_fast(acc[mt][nt][r] + bias[nt]));
        }
      }
  }
  __syncthreads();

  // ---- Layer 2: K=512 (32 kk), wave tile 64x64 ----
  #pragma unroll
  for (int mt = 0; mt < 2; ++mt)
    #pragma unroll
    for (int nt = 0; nt < 2; ++nt)
      #pragma unroll
      for (int r = 0; r < 16; ++r) acc[mt][nt][r] = 0.f;

  {
    const s16x8* b0p = (const s16x8*)w2p + (size_t)(w * 2) * 32 * 64 + lane;
    const s16x8* b1p = b0p + 32 * 64;
    #pragma unroll 8
    for (int kk = 0; kk < 32; ++kk) {
      int ch = kk * 2 + khalf;
      s16x8 a0 = *(const s16x8*)&lds[LDSIDX(ch, ln31)];
      s16x8 a1 = *(const s16x8*)&lds[LDSIDX(ch, 32 + ln31)];
      s16x8 b0 = b0p[kk * 64];
      s16x8 b1 = b1p[kk * 64];
      acc[0][0] = __builtin_amdgcn_mfma_f32_32x32x16_bf16(a0, b0, acc[0][0], 0, 0, 0);
      acc[0][1] = __builtin_amdgcn_mfma_f32_32x32x16_bf16(a0, b1, acc[0][1], 0, 0, 0);
      acc[1][0] = __builtin_amdgcn_mfma_f32_32x32x16_bf16(a1, b0, acc[1][0], 0, 0, 0);
      acc[1][1] = __builtin_amdgcn_mfma_f32_32x32x16_bf16(a1, b1, acc[1][1], 0, 0, 0);
    }
  }
  __syncthreads();

  {
    float bias[2];
    bias[0] = b2[ncb + ln31];
    bias[1] = b2[ncb + 32 + ln31];
    #pragma unroll
    for (int mt = 0; mt < 2; ++mt)
      #pragma unroll
      for (int nt = 0; nt < 2; ++nt) {
        int hc = ncb + nt * 32 + ln31;
        int chh = hc >> 3, wi = hc & 7;
        #pragma unroll
        for (int r = 0; r < 16; ++r) {
          int m = mt * 32 + (r & 3) + 8 * (r >> 2) + 4 * khalf;
          lds[(chh << 9) + (((m + chh) & 63) << 3) + wi] =
              f2bf(tanh_fast(acc[mt][nt][r] + bias[nt]));
        }
      }
  }
  __syncthreads();

  // ---- Layer 3: out 64x128, wave: mt=(w&1), cols (w>>1)*32, K=512 ----
  {
    f32x16 acc3;
    #pragma unroll
    for (int r = 0; r < 16; ++r) acc3[r] = 0.f;
    const int mb = (w & 1) * 32;
    const int t3 = w >> 1;
    const s16x8* bp = (const s16x8*)w3p + (size_t)t3 * 32 * 64 + lane;
    #pragma unroll 8
    for (int kk = 0; kk < 32; ++kk) {
      int ch = kk * 2 + khalf;
      s16x8 a = *(const s16x8*)&lds[LDSIDX(ch, mb + ln31)];
      s16x8 b = bp[kk * 64];
      acc3 = __builtin_amdgcn_mfma_f32_32x32x16_bf16(a, b, acc3, 0, 0, 0);
    }
    float bz = b3[t3 * 32 + ln31];
    #pragma unroll
    for (int r = 0; r < 16; ++r) {
      int m = m0 + mb + (r & 3) + 8 * (r >> 2) + 4 * khalf;
      out[(size_t)m * 128 + t3 * 32 + ln31] = acc3[r] + bz;
    }
  }
}

extern "C" void kernel_launch(void* const* d_in, const int* in_sizes, int n_in,
                              void* d_out, int out_size, void* d_ws, size_t ws_size,
                              hipStream_t stream) {
  const float* x  = (const float*)d_in[0];
  const float* W1 = (const float*)d_in[1];
  const float* b1 = (const float*)d_in[2];
  const float* W2 = (const float*)d_in[3];
  const float* b2 = (const float*)d_in[4];
  const float* W3 = (const float*)d_in[5];
  const float* b3 = (const float*)d_in[6];
  float* out = (float*)d_out;
  unsigned short* ws = (unsigned short*)d_ws;   // 458752 bf16 = 896KB

  hipLaunchKernelGGL(prep_pack, dim3(224), dim3(256), 0, stream, W1, W2, W3, ws);
  hipLaunchKernelGGL(mlp_limit_kernel, dim3(2048), dim3(512), 0, stream,
                     x, b1, b2, b3, ws, ws + 131072, ws + 393216, out);
}

// Round 3
// 383.502 us; speedup vs baseline: 1.1673x; 1.0284x over previous
//
#include <hip/hip_runtime.h>

typedef short s16x8 __attribute__((ext_vector_type(8)));
typedef unsigned short u16x8 __attribute__((ext_vector_type(8)));
typedef float f32x16 __attribute__((ext_vector_type(16)));

__device__ __forceinline__ unsigned short f2bf(float f) {
  unsigned u = __float_as_uint(f);
  u += 0x7fffu + ((u >> 16) & 1u);            // round-to-nearest-even
  return (unsigned short)(u >> 16);
}

__device__ __forceinline__ float tanh_fast(float x) {
  float xc = fminf(15.f, fmaxf(-15.f, x));
  float t = __builtin_amdgcn_exp2f(xc * 2.8853900817779268f); // 2*log2(e)
  return (t - 1.f) * __builtin_amdgcn_rcpf(t + 1.f);
}

// ---- prep: pack W (K,N) fp32 -> bf16 MFMA-B-fragment order, via LDS transpose ----
// Packed layout: chunk c = ((tile*KK + kk)*64 + lane), elems j=0..7:
//   value = W[(kk*16 + (lane>>5)*8 + j) * N + tile*32 + (lane&31)]
// w1p: 16 tiles x 16 kk at ws+0 ; w2p: 16 x 32 at ws+131072 ; w3p: 4 x 32 at ws+393216
// Each block transposes one 64k x 64n tile: coalesced reads, coalesced packed writes.
__global__ __launch_bounds__(256)
void prep_pack(const float* __restrict__ W1, const float* __restrict__ W2,
               const float* __restrict__ W3, unsigned short* __restrict__ ws) {
  __shared__ unsigned short t[64][65];
  const int b = blockIdx.x;
  const float* W; unsigned short* base; int KK, N, tk, tn;
  if (b < 32)      { W = W1; base = ws;          KK = 16; N = 512; tk = b >> 3;       tn = b & 7; }
  else if (b < 96) { int g = b - 32; W = W2; base = ws + 131072; KK = 32; N = 512; tk = g >> 3; tn = g & 7; }
  else             { int g = b - 96; W = W3; base = ws + 393216; KK = 32; N = 128; tk = g >> 1; tn = g & 1; }

  const int tid = threadIdx.x;
  // read 64x64 fp32 tile, coalesced (4 rows x 64 cols per pass)
  #pragma unroll
  for (int p = 0; p < 16; ++p) {
    int kl = p * 4 + (tid >> 6);
    int nl = tid & 63;
    t[kl][nl] = f2bf(W[(size_t)(tk * 64 + kl) * N + tn * 64 + nl]);
  }
  __syncthreads();

  // write 8 packed chunks (2 n-subtiles x 4 kk), 16B/thread coalesced
  const int lane = tid & 63, ln31 = lane & 31, khalf = lane >> 5;
  #pragma unroll
  for (int pass = 0; pass < 2; ++pass) {
    int pair = pass * 4 + (tid >> 6);     // 0..7
    int tn_l = pair & 1, kk_l = pair >> 1;
    int tile = tn * 2 + tn_l, kk = tk * 4 + kk_l;
    u16x8 v;
    #pragma unroll
    for (int j = 0; j < 8; ++j)
      v[j] = t[kk_l * 16 + khalf * 8 + j][tn_l * 32 + ln31];
    *(u16x8*)(base + ((size_t)(tile * KK + kk) * 64 + lane) * 8) = v;
  }
}

// LDS layout: chunk-major with row rotation.
// element addr (shorts) = ch*512 + ((row+ch)&63)*8 + within
#define LDSIDX(ch, row) (((ch) << 9) + ((((row) + (ch)) & 63) << 3))

__global__ __launch_bounds__(512, 4)
void mlp_limit_kernel(const float* __restrict__ x,
                      const float* __restrict__ b1, const float* __restrict__ b2,
                      const float* __restrict__ b3,
                      const unsigned short* __restrict__ w1p,
                      const unsigned short* __restrict__ w2p,
                      const unsigned short* __restrict__ w3p,
                      float* __restrict__ out) {
  __shared__ __align__(16) unsigned short lds[64 * 512];  // 64KB
  const int tid   = threadIdx.x;
  const int w     = tid >> 6;          // 8 waves
  const int lane  = tid & 63;
  const int ln31  = lane & 31;
  const int khalf = lane >> 5;
  const int m0    = blockIdx.x * 64;

  // ---- stage x tile: 64 rows x 32 chunks (fp32 -> bf16) ----
  #pragma unroll
  for (int c = tid; c < 2048; c += 512) {
    int row = c >> 5, ch = c & 31;
    const float4* src = (const float4*)(x + (size_t)(m0 + row) * 256 + ch * 8);
    float4 f0 = src[0], f1 = src[1];
    u16x8 v;
    v[0] = f2bf(f0.x); v[1] = f2bf(f0.y); v[2] = f2bf(f0.z); v[3] = f2bf(f0.w);
    v[4] = f2bf(f1.x); v[5] = f2bf(f1.y); v[6] = f2bf(f1.z); v[7] = f2bf(f1.w);
    *(u16x8*)&lds[LDSIDX(ch, row)] = v;
  }
  __syncthreads();

  const int ncb = w * 64;              // this wave's 64 hidden cols

  f32x16 acc[2][2];
  #pragma unroll
  for (int mt = 0; mt < 2; ++mt)
    #pragma unroll
    for (int nt = 0; nt < 2; ++nt)
      #pragma unroll
      for (int r = 0; r < 16; ++r) acc[mt][nt][r] = 0.f;

  // ---- Layer 1: K=256 (16 kk), wave tile 64x64 ----
  {
    const s16x8* b0p = (const s16x8*)w1p + (size_t)(w * 2) * 16 * 64 + lane;
    const s16x8* b1p = b0p + 16 * 64;
    #pragma unroll 2
    for (int kk = 0; kk < 16; ++kk) {
      int ch = kk * 2 + khalf;
      s16x8 a0 = *(const s16x8*)&lds[LDSIDX(ch, ln31)];
      s16x8 a1 = *(const s16x8*)&lds[LDSIDX(ch, 32 + ln31)];
      s16x8 b0 = b0p[kk * 64];
      s16x8 b1 = b1p[kk * 64];
      acc[0][0] = __builtin_amdgcn_mfma_f32_32x32x16_bf16(a0, b0, acc[0][0], 0, 0, 0);
      acc[0][1] = __builtin_amdgcn_mfma_f32_32x32x16_bf16(a0, b1, acc[0][1], 0, 0, 0);
      acc[1][0] = __builtin_amdgcn_mfma_f32_32x32x16_bf16(a1, b0, acc[1][0], 0, 0, 0);
      acc[1][1] = __builtin_amdgcn_mfma_f32_32x32x16_bf16(a1, b1, acc[1][1], 0, 0, 0);
    }
  }
  __syncthreads();

  {
    float bias[2];
    bias[0] = b1[ncb + ln31];
    bias[1] = b1[ncb + 32 + ln31];
    #pragma unroll
    for (int mt = 0; mt < 2; ++mt)
      #pragma unroll
      for (int nt = 0; nt < 2; ++nt) {
        int hc = ncb + nt * 32 + ln31;
        int chh = hc >> 3, wi = hc & 7;
        #pragma unroll
        for (int r = 0; r < 16; ++r) {
          int m = mt * 32 + (r & 3) + 8 * (r >> 2) + 4 * khalf;
          lds[(chh << 9) + (((m + chh) & 63) << 3) + wi] =
              f2bf(tanh_fast(acc[mt][nt][r] + bias[nt]));
        }
      }
  }
  __syncthreads();

  // ---- Layer 2: K=512 (32 kk), wave tile 64x64 ----
  #pragma unroll
  for (int mt = 0; mt < 2; ++mt)
    #pragma unroll
    for (int nt = 0; nt < 2; ++nt)
      #pragma unroll
      for (int r = 0; r < 16; ++r) acc[mt][nt][r] = 0.f;

  {
    const s16x8* b0p = (const s16x8*)w2p + (size_t)(w * 2) * 32 * 64 + lane;
    const s16x8* b1p = b0p + 32 * 64;
    #pragma unroll 2
    for (int kk = 0; kk < 32; ++kk) {
      int ch = kk * 2 + khalf;
      s16x8 a0 = *(const s16x8*)&lds[LDSIDX(ch, ln31)];
      s16x8 a1 = *(const s16x8*)&lds[LDSIDX(ch, 32 + ln31)];
      s16x8 b0 = b0p[kk * 64];
      s16x8 b1 = b1p[kk * 64];
      acc[0][0] = __builtin_amdgcn_mfma_f32_32x32x16_bf16(a0, b0, acc[0][0], 0, 0, 0);
      acc[0][1] = __builtin_amdgcn_mfma_f32_32x32x16_bf16(a0, b1, acc[0][1], 0, 0, 0);
      acc[1][0] = __builtin_amdgcn_mfma_f32_32x32x16_bf16(a1, b0, acc[1][0], 0, 0, 0);
      acc[1][1] = __builtin_amdgcn_mfma_f32_32x32x16_bf16(a1, b1, acc[1][1], 0, 0, 0);
    }
  }
  __syncthreads();

  {
    float bias[2];
    bias[0] = b2[ncb + ln31];
    bias[1] = b2[ncb + 32 + ln31];
    #pragma unroll
    for (int mt = 0; mt < 2; ++mt)
      #pragma unroll
      for (int nt = 0; nt < 2; ++nt) {
        int hc = ncb + nt * 32 + ln31;
        int chh = hc >> 3, wi = hc & 7;
        #pragma unroll
        for (int r = 0; r < 16; ++r) {
          int m = mt * 32 + (r & 3) + 8 * (r >> 2) + 4 * khalf;
          lds[(chh << 9) + (((m + chh) & 63) << 3) + wi] =
              f2bf(tanh_fast(acc[mt][nt][r] + bias[nt]));
        }
      }
  }
  __syncthreads();

  // ---- Layer 3: out 64x128, wave: rows (w&1)*32, cols (w>>1)*32, K=512 ----
  {
    f32x16 acc3;
    #pragma unroll
    for (int r = 0; r < 16; ++r) acc3[r] = 0.f;
    const int mb = (w & 1) * 32;
    const int t3 = w >> 1;
    const s16x8* bp = (const s16x8*)w3p + (size_t)t3 * 32 * 64 + lane;
    #pragma unroll 2
    for (int kk = 0; kk < 32; ++kk) {
      int ch = kk * 2 + khalf;
      s16x8 a = *(const s16x8*)&lds[LDSIDX(ch, mb + ln31)];
      s16x8 b = bp[kk * 64];
      acc3 = __builtin_amdgcn_mfma_f32_32x32x16_bf16(a, b, acc3, 0, 0, 0);
    }
    float bz = b3[t3 * 32 + ln31];
    #pragma unroll
    for (int r = 0; r < 16; ++r) {
      int m = m0 + mb + (r & 3) + 8 * (r >> 2) + 4 * khalf;
      out[(size_t)m * 128 + t3 * 32 + ln31] = acc3[r] + bz;
    }
  }
}

extern "C" void kernel_launch(void* const* d_in, const int* in_sizes, int n_in,
                              void* d_out, int out_size, void* d_ws, size_t ws_size,
                              hipStream_t stream) {
  const float* x  = (const float*)d_in[0];
  const float* W1 = (const float*)d_in[1];
  const float* b1 = (const float*)d_in[2];
  const float* W2 = (const float*)d_in[3];
  const float* b2 = (const float*)d_in[4];
  const float* W3 = (const float*)d_in[5];
  const float* b3 = (const float*)d_in[6];
  float* out = (float*)d_out;
  unsigned short* ws = (unsigned short*)d_ws;   // 458752 bf16 = 896KB

  hipLaunchKernelGGL(prep_pack, dim3(112), dim3(256), 0, stream, W1, W2, W3, ws);
  hipLaunchKernelGGL(mlp_limit_kernel, dim3(2048), dim3(512), 0, stream,
                     x, b1, b2, b3, ws, ws + 131072, ws + 393216, out);
}